// Round 18
// baseline (5948.692 us; speedup 1.0000x reference)
//
#include <hip/hip_runtime.h>

using short8 = __attribute__((ext_vector_type(8))) short;
using f32x4  = __attribute__((ext_vector_type(4))) float;
using uint4v = __attribute__((ext_vector_type(4))) unsigned;

#define NT     512
#define NBATCH 64
#define NN     1024
#define NIN    24
#define NG     8                      // groups of 8 batches
#define ROWS   8
#define TILE32 (ROWS * NN)            // u32 per group tile (32 KB)
#define PARSTRIDE (NG * TILE32)       // u32 per parity buffer (256 KB)
#define SCOPE_AGENT __HIP_MEMORY_SCOPE_AGENT
#define RETRY_CAP (1 << 17)           // fail loud (absmax), never hang

// Epoch-in-data sync (R13) + K-split (R15) + TWO-GROUP PREFETCH PIPELINE
// (R17): each group's tagged A-loads are ISSUED one phase before consumption,
// so publish->L3-visibility hides under the other group's compute. Tag checks
// make every mis-timing (incl. compiler reg copies of in-flight loads)
// degrade to a retry, never corruption: stale regs hold an older tag.

__device__ __forceinline__ unsigned short f2bf(float x) {
  union { float f; unsigned u; } v; v.f = x;
  return (unsigned short)((v.u + 0x7FFFu + ((v.u >> 16) & 1u)) >> 16);
}
__device__ __forceinline__ f32x4 MF(short8 a, short8 b, f32x4 c) {
  return __builtin_amdgcn_mfma_f32_16x16x32_bf16(a, b, c, 0, 0, 0);
}

#define PACKS8(dst, Rx, Ry) do { \
  union { unsigned u[4]; short8 s; } pk_; \
  pk_.u[0] = (Rx[0] & 0xFFFFu) | (Rx[1] << 16); \
  pk_.u[1] = (Rx[2] & 0xFFFFu) | (Rx[3] << 16); \
  pk_.u[2] = (Ry[0] & 0xFFFFu) | (Ry[1] << 16); \
  pk_.u[3] = (Ry[2] & 0xFFFFu) | (Ry[3] << 16); \
  dst = pk_.s; } while (0)

// issue 8 tagged dwordx4 loads (one wave K-slice x 8 rows), NO wait
#define PF_ISSUE(P, gp) asm volatile( \
  "global_load_dwordx4 %0, %8, off sc0 sc1\n\t" \
  "global_load_dwordx4 %1, %8, off offset:16 sc0 sc1\n\t" \
  "global_load_dwordx4 %2, %8, off offset:128 sc0 sc1\n\t" \
  "global_load_dwordx4 %3, %8, off offset:144 sc0 sc1\n\t" \
  "global_load_dwordx4 %4, %8, off offset:256 sc0 sc1\n\t" \
  "global_load_dwordx4 %5, %8, off offset:272 sc0 sc1\n\t" \
  "global_load_dwordx4 %6, %8, off offset:384 sc0 sc1\n\t" \
  "global_load_dwordx4 %7, %8, off offset:400 sc0 sc1" \
  : "=&v"(P##0), "=&v"(P##1), "=&v"(P##2), "=&v"(P##3), \
    "=&v"(P##4), "=&v"(P##5), "=&v"(P##6), "=&v"(P##7) \
  : "v"(gp) : "memory")

#define TAGBAD(P) (((P[0]>>16)^tag)|((P[1]>>16)^tag)|((P[2]>>16)^tag)|((P[3]>>16)^tag))

// drain, check tags of the prefetched set, retry (reissue+drain) if stale
#define PF_CONSUME(P, gp) do { int guard_ = 0; for (;;) { \
    asm volatile("s_waitcnt vmcnt(0)" ::: "memory"); \
    __builtin_amdgcn_sched_barrier(0); \
    unsigned bad_ = TAGBAD(P##0) | TAGBAD(P##1) | TAGBAD(P##2) | TAGBAD(P##3) \
                  | TAGBAD(P##4) | TAGBAD(P##5) | TAGBAD(P##6) | TAGBAD(P##7); \
    if (__all((int)(bad_ == 0))) break; \
    if (++guard_ > RETRY_CAP) break; \
    PF_ISSUE(P, gp); } } while (0)

// 32 blocks x 512 thr (8 waves). slot=bid>>2 owns neurons [128*slot,+128);
// wave w = K-slice [128w,+128) for partials, owns output col-set w.
// Pair p=bid&3 serves groups gA=p (batches [8p,+8)) and gB=p+4, alternating.
__global__ __launch_bounds__(512, 1) void rnn_step_all(
    const float* __restrict__ u, const float* __restrict__ r0,
    const float* __restrict__ W, const float* __restrict__ Bm,
    const float* __restrict__ tau, const float* __restrict__ ds,
    float* __restrict__ out, unsigned* __restrict__ obs32)
{
  __shared__ f32x4 pl[2][64][32];   // 2 x 32 KB partial tiles

  const int tid  = threadIdx.x;
  const int wave = tid >> 6;
  const int lane = tid & 63;
  const int bid  = blockIdx.x;
  const int gA   = bid & 3, gB = gA + 4;
  const int slot = bid >> 2;
  const int b0A  = gA * ROWS, b0B = gB * ROWS;
  const int lr = lane & 15, lg = lane >> 4;
  const int i  = slot * 128 + wave * 16 + lr;   // OUTPUT neuron (col-set = wave)

  // ---- W fragments: 8 col-sets x this wave's K-slice (group-independent) ----
  short8 wf[8][4];
#pragma unroll
  for (int c = 0; c < 8; ++c) {
#pragma unroll
    for (int j = 0; j < 4; ++j) {
      const int col = slot * 128 + c * 16 + lr;
      const int k0  = wave * 128 + j * 32 + lg * 8;
      f32x4 w0 = *(const f32x4*)(W + (size_t)col * NN + k0);
      f32x4 w1 = *(const f32x4*)(W + (size_t)col * NN + k0 + 4);
      f32x4 s0 = *(const f32x4*)(ds + k0);
      f32x4 s1 = *(const f32x4*)(ds + k0 + 4);
      short8 f;
      f[0]=(short)f2bf(w0[0]*s0[0]); f[1]=(short)f2bf(w0[1]*s0[1]);
      f[2]=(short)f2bf(w0[2]*s0[2]); f[3]=(short)f2bf(w0[3]*s0[3]);
      f[4]=(short)f2bf(w1[0]*s1[0]); f[5]=(short)f2bf(w1[1]*s1[1]);
      f[6]=(short)f2bf(w1[2]*s1[2]); f[7]=(short)f2bf(w1[3]*s1[3]);
      wf[c][j] = f;
    }
  }
  short8 bin;
#pragma unroll
  for (int e = 0; e < 8; ++e) {
    const int m = lg * 8 + e;
    bin[e] = (short)f2bf(m < NIN ? Bm[(size_t)i * NIN + m] : 0.0f);
  }
  const float itau = 1.0f / tau[i];

  unsigned* gtA0 = obs32 + gA * TILE32;
  unsigned* gtA1 = gtA0 + PARSTRIDE;
  unsigned* gtB0 = obs32 + gB * TILE32;
  unsigned* gtB1 = gtB0 + PARSTRIDE;

  // ---- init r; publish tag 1 into parity 0 (both groups) ----
  f32x4 rA = {0,0,0,0}, rB = {0,0,0,0};
  if (lg < 2) {
#pragma unroll
    for (int q = 0; q < 4; ++q) {
      const int row = lg * 4 + q;
      rA[q] = r0[(size_t)(b0A + row) * NN + i];
      rB[q] = r0[(size_t)(b0B + row) * NN + i];
      __hip_atomic_store(&gtA0[row * NN + i],
                         (unsigned)f2bf(fmaxf(rA[q], 0.f)) | (1u << 16),
                         __ATOMIC_RELAXED, SCOPE_AGENT);
      __hip_atomic_store(&gtB0[row * NN + i],
                         (unsigned)f2bf(fmaxf(rB[q], 0.f)) | (1u << 16),
                         __ATOMIC_RELAXED, SCOPE_AGENT);
    }
  }

  const float* ubA = u + (size_t)(b0A + (lr & 7)) * NT * NIN;
  const float* ubB = u + (size_t)(b0B + (lr & 7)) * NT * NIN;
  f32x4 uA0={0,0,0,0}, uA1={0,0,0,0}, uB0={0,0,0,0}, uB1={0,0,0,0};
  if (lr < 8 && lg < 3) {
    uA0 = *(const f32x4*)(ubA + lg * 8); uA1 = *(const f32x4*)(ubA + lg * 8 + 4);
    uB0 = *(const f32x4*)(ubB + lg * 8); uB1 = *(const f32x4*)(ubB + lg * 8 + 4);
  }

  // ---- prefetch registers + initial issue (parity 0, expect tag 1) ----
  uint4v PA0,PA1,PA2,PA3,PA4,PA5,PA6,PA7;
  uint4v PB0,PB1,PB2,PB3,PB4,PB5,PB6,PB7;
  const int pfoff = (lr & 7) * NN + wave * 128 + lg * 8;
  const unsigned* pfA = gtA0 + pfoff;
  const unsigned* pfB = gtB0 + pfoff;
  PF_ISSUE(PA, pfA);
  PF_ISSUE(PB, pfB);

  for (int t = 0; t < NT; ++t) {
    const unsigned tag  = (unsigned)(t + 1);
    const unsigned tag2 = (unsigned)(t + 2);
    const bool last = (t == NT - 1);

#define PHASE(PP, P, PFP, WRT, RST, U0, U1, UB, B0) do {                       \
    PF_CONSUME(P, PFP);                                                        \
    short8 af0, af1, af2, af3;                                                 \
    PACKS8(af0, P##0, P##1); PACKS8(af1, P##2, P##3);                          \
    PACKS8(af2, P##4, P##5); PACKS8(af3, P##6, P##7);                          \
    _Pragma("unroll")                                                          \
    for (int c = 0; c < 8; ++c) {                                              \
      f32x4 p = {0,0,0,0};                                                     \
      p = MF(af0, wf[c][0], p); p = MF(af1, wf[c][1], p);                      \
      p = MF(af2, wf[c][2], p); p = MF(af3, wf[c][3], p);                      \
      if (lg < 2) pl[PP][c * 8 + wave][lane] = p;                              \
    }                                                                          \
    __syncthreads();                                                           \
    f32x4 acc = {0,0,0,0};                                                     \
    if (lg < 2) {                                                              \
      acc = pl[PP][wave * 8 + 0][lane];                                        \
      _Pragma("unroll")                                                        \
      for (int s = 1; s < 8; ++s) acc += pl[PP][wave * 8 + s][lane];           \
    }                                                                          \
    short8 ua;                                                                 \
    ua[0]=(short)f2bf(U0[0]); ua[1]=(short)f2bf(U0[1]);                        \
    ua[2]=(short)f2bf(U0[2]); ua[3]=(short)f2bf(U0[3]);                        \
    ua[4]=(short)f2bf(U1[0]); ua[5]=(short)f2bf(U1[1]);                        \
    ua[6]=(short)f2bf(U1[2]); ua[7]=(short)f2bf(U1[3]);                        \
    if (lr >= 8 || lg >= 3) ua = short8{0,0,0,0,0,0,0,0};                      \
    acc = MF(ua, bin, acc);                                                    \
    f32x4 rv;                                                                  \
    _Pragma("unroll")                                                          \
    for (int q = 0; q < 4; ++q) {                                              \
      const float act = 60.0f / (1.0f + expf(8.4f - 0.28f * acc[q]));          \
      rv[q] = RST[q] + (0.1f * (act - RST[q])) * itau;                         \
      RST[q] = rv[q];                                                          \
    }                                                                          \
    if (!last) {                                                               \
      if (lg < 2) {                                                            \
        _Pragma("unroll")                                                      \
        for (int q = 0; q < 4; ++q)                                            \
          __hip_atomic_store(&(WRT)[(lg * 4 + q) * NN + i],                    \
              (unsigned)f2bf(fmaxf(rv[q], 0.f)) | (tag2 << 16),                \
              __ATOMIC_RELAXED, SCOPE_AGENT);                                  \
      }                                                                        \
      if (lr < 8 && lg < 3) {                                                  \
        const float* up_ = (UB) + (t + 1) * NIN + lg * 8;                      \
        U0 = *(const f32x4*)(up_); U1 = *(const f32x4*)(up_ + 4);              \
      }                                                                        \
      PFP = (WRT) + pfoff;                                                     \
      PF_ISSUE(P, PFP);                                                        \
    }                                                                          \
    if (lg < 2) {                                                              \
      _Pragma("unroll")                                                        \
      for (int q = 0; q < 4; ++q)                                              \
        out[((size_t)((B0) + lg * 4 + q) * NT + t) * NN + i] = rv[q];          \
    }                                                                          \
  } while (0)

    unsigned* wrtA = (t & 1) ? gtA0 : gtA1;
    unsigned* wrtB = (t & 1) ? gtB0 : gtB1;
    PHASE(0, PA, pfA, wrtA, rA, uA0, uA1, ubA, b0A);
    PHASE(1, PB, pfB, wrtB, rB, uB0, uB1, ubB, b0B);
#undef PHASE
  }

  // r_final (both groups)
  if (lg < 2) {
    const size_t fbase = (size_t)NBATCH * NT * NN;
#pragma unroll
    for (int q = 0; q < 4; ++q) {
      const int row = lg * 4 + q;
      out[fbase + (size_t)(b0A + row) * NN + i] = rA[q];
      out[fbase + (size_t)(b0B + row) * NN + i] = rB[q];
    }
  }
}

extern "C" void kernel_launch(void* const* d_in, const int* in_sizes, int n_in,
                              void* d_out, int out_size, void* d_ws, size_t ws_size,
                              hipStream_t stream) {
  const float* u   = (const float*)d_in[0];
  const float* r0  = (const float*)d_in[1];
  const float* W   = (const float*)d_in[2];
  const float* Bm  = (const float*)d_in[3];
  const float* tau = (const float*)d_in[4];
  const float* ds  = (const float*)d_in[5];
  float* out = (float*)d_out;

  unsigned* obs32 = (unsigned*)d_ws;

  // zero both epoch-tagged buffers every call (tags restart at 1 -> deterministic)
  hipMemsetAsync(d_ws, 0, 2 * PARSTRIDE * sizeof(unsigned), stream);

  rnn_step_all<<<dim3(32), dim3(512), 0, stream>>>(u, r0, W, Bm, tau, ds,
                                                   out, obs32);
}

// Round 19
// 1675.984 us; speedup vs baseline: 3.5494x; 3.5494x over previous
//
#include <hip/hip_runtime.h>

using short8 = __attribute__((ext_vector_type(8))) short;
using f32x4  = __attribute__((ext_vector_type(4))) float;
using uint4v = __attribute__((ext_vector_type(4))) unsigned;

#define NT     512
#define NBATCH 64
#define NN     1024
#define NIN    24
#define NG     4                      // groups of 16 batches
#define NSLOT  8                      // 128 neurons per slot-block
#define ROWS   16
#define OBS32  (NG * ROWS * NN)       // u32 per ping-pong buffer (256 KB)
#define SCOPE_AGENT __HIP_MEMORY_SCOPE_AGENT
#define RETRY_CAP (1 << 17)           // fail loud (absmax), never hang

// R18 = R13 (best: 1995 us) + CLOCK-PACED staging. s_memrealtime is a
// constant-rate counter common to all CUs; after the init exchange aligns
// blocks to ~1 us, each block gates step t's stage at T0 + (t+2)*P with
// P ~ 1.8 us >= compute + publish + L3 visibility. Consumers then load ONCE
// per step on schedule -> no retry cascade (R13's ~3.9 us/step was ~2-3
// stale rounds from skew feedback). Wrong P degrades exactly to R13
// (tags still validated, caps intact). Also: expf -> native exp2f.

__device__ __forceinline__ unsigned short f2bf(float x) {
  union { float f; unsigned u; } v; v.f = x;
  return (unsigned short)((v.u + 0x7FFFu + ((v.u >> 16) & 1u)) >> 16);
}
__device__ __forceinline__ f32x4 MF(short8 a, short8 b, f32x4 c) {
  return __builtin_amdgcn_mfma_f32_16x16x32_bf16(a, b, c, 0, 0, 0);
}

// 32 blocks x 512 thr (8 waves). Group g = bid&3 owns batches [16g,+16);
// slot = bid>>2 owns neurons [128*slot,+128); wave w owns 16 of them.
// W fragments persistent in registers (128 VGPR). Placement-independent.
__global__ __launch_bounds__(512, 1) void rnn_step_all(
    const float* __restrict__ u, const float* __restrict__ r0,
    const float* __restrict__ W, const float* __restrict__ Bm,
    const float* __restrict__ tau, const float* __restrict__ ds,
    float* __restrict__ out, unsigned* __restrict__ obs32,
    unsigned long long P_ticks)
{
  __shared__ unsigned long long lds64[ROWS * 2048 / 8];  // 32 KB staged A-tile
  char* ldsb = (char*)lds64;

  const int tid  = threadIdx.x;
  const int lane = tid & 63;
  const int bid  = blockIdx.x;
  const int g    = bid & 3;
  const int slot = bid >> 2;
  const int b0   = g * ROWS;
  const int lr = lane & 15, lg = lane >> 4;
  const int wave = tid >> 6;
  const int i  = slot * 128 + wave * 16 + lr;   // this lane's neuron

  // loader assignment: thread covers row mrow, u32 cols [4*mc + 128*m]
  const int mrow = tid >> 5;                    // 0..15
  const int mc   = tid & 31;                    // 0..31

  // ---- persistent W fragments: B[k][col] = W[i0+col][kb*32+k]*sign ----
  short8 wf[32];
#pragma unroll
  for (int kb = 0; kb < 32; ++kb) {
    const int j0 = kb * 32 + lg * 8;
    const float* wp = W + (size_t)i * NN + j0;
    f32x4 w0 = *(const f32x4*)(wp);
    f32x4 w1 = *(const f32x4*)(wp + 4);
    f32x4 s0 = *(const f32x4*)(ds + j0);
    f32x4 s1 = *(const f32x4*)(ds + j0 + 4);
    short8 f;
    f[0]=(short)f2bf(w0[0]*s0[0]); f[1]=(short)f2bf(w0[1]*s0[1]);
    f[2]=(short)f2bf(w0[2]*s0[2]); f[3]=(short)f2bf(w0[3]*s0[3]);
    f[4]=(short)f2bf(w1[0]*s1[0]); f[5]=(short)f2bf(w1[1]*s1[1]);
    f[6]=(short)f2bf(w1[2]*s1[2]); f[7]=(short)f2bf(w1[3]*s1[3]);
    wf[kb] = f;
  }
  short8 bin;
#pragma unroll
  for (int e = 0; e < 8; ++e) {
    const int m = lg * 8 + e;
    bin[e] = (short)f2bf(m < NIN ? Bm[(size_t)i * NIN + m] : 0.0f);
  }
  const float itau = 1.0f / tau[i];

  unsigned* gt0 = obs32 + g * (ROWS * NN);          // parity-0 tile (this group)
  unsigned* gt1 = obs32 + OBS32 + g * (ROWS * NN);  // parity-1 tile

  // pace + poll + validate + stage into LDS (all 512 threads; 64 KB -> 32 KB)
  auto stage = [&](const unsigned* gtile, unsigned tag, unsigned long long gate) {
    if (gate) {
      for (;;) {
        unsigned long long now = __builtin_amdgcn_s_memrealtime();
        if (now >= gate) break;
        __builtin_amdgcn_s_sleep(2);
      }
    }
    const unsigned* gp = gtile + mrow * NN + mc * 4;
    uint4v R0, R1, R2, R3, R4, R5, R6, R7;
    int guard = 0;
    for (;;) {
      asm volatile(
          "global_load_dwordx4 %0, %8, off sc0 sc1\n\t"
          "global_load_dwordx4 %1, %8, off offset:512 sc0 sc1\n\t"
          "global_load_dwordx4 %2, %8, off offset:1024 sc0 sc1\n\t"
          "global_load_dwordx4 %3, %8, off offset:1536 sc0 sc1\n\t"
          "global_load_dwordx4 %4, %8, off offset:2048 sc0 sc1\n\t"
          "global_load_dwordx4 %5, %8, off offset:2560 sc0 sc1\n\t"
          "global_load_dwordx4 %6, %8, off offset:3072 sc0 sc1\n\t"
          "global_load_dwordx4 %7, %8, off offset:3584 sc0 sc1\n\t"
          "s_waitcnt vmcnt(0)"
          : "=&v"(R0), "=&v"(R1), "=&v"(R2), "=&v"(R3),
            "=&v"(R4), "=&v"(R5), "=&v"(R6), "=&v"(R7)
          : "v"(gp) : "memory");
      unsigned bad = 0;
#define CK(Rx) bad |= ((Rx[0] >> 16) ^ tag) | ((Rx[1] >> 16) ^ tag) | \
                      ((Rx[2] >> 16) ^ tag) | ((Rx[3] >> 16) ^ tag)
      CK(R0); CK(R1); CK(R2); CK(R3); CK(R4); CK(R5); CK(R6); CK(R7);
#undef CK
      if (__all((int)(bad == 0))) break;
      if (++guard > RETRY_CAP) break;   // fail loud, never hang
    }
    const int rbm = (mrow & 7) << 4;
    char* wrow = ldsb + mrow * 2048;
#define WR(Rx, m) do { \
      unsigned lo = (Rx[0] & 0xFFFFu) | (Rx[1] << 16); \
      unsigned hi = (Rx[2] & 0xFFFFu) | (Rx[3] << 16); \
      *(unsigned long long*)(wrow + (((m) * 256 + 8 * mc) ^ rbm)) = \
          ((unsigned long long)hi << 32) | (unsigned long long)lo; \
    } while (0)
    WR(R0, 0); WR(R1, 1); WR(R2, 2); WR(R3, 3);
    WR(R4, 4); WR(R5, 5); WR(R6, 6); WR(R7, 7);
#undef WR
  };

  // ---- init r (C/D: row(batch)=lg*4+q, col=lr); publish r0 obs, tag 1 ----
  f32x4 r;
#pragma unroll
  for (int q = 0; q < 4; ++q) {
    const int row = lg * 4 + q;
    r[q] = r0[(size_t)(b0 + row) * NN + i];
    const unsigned vv = (unsigned)f2bf(r[q] > 0.0f ? r[q] : 0.0f) | (1u << 16);
    __hip_atomic_store(&gt0[row * NN + i], vv, __ATOMIC_RELAXED, SCOPE_AGENT);
  }

  const float* up_base = u + (size_t)(b0 + lr) * NT * NIN;
  f32x4 up0 = {0.f,0.f,0.f,0.f}, up1 = {0.f,0.f,0.f,0.f};
  if (lg < 3) {
    up0 = *(const f32x4*)(up_base + lg * 8);
    up1 = *(const f32x4*)(up_base + lg * 8 + 4);
  }

  stage(gt0, 1u, 0ull);   // init exchange aligns all blocks to ~1 us
  __syncthreads();

  // common time base: all blocks exit the init exchange within ~1 us of each
  // other; P's margin absorbs that skew.
  const unsigned long long T0 = __builtin_amdgcn_s_memrealtime();

  const char* lrow = ldsb + lr * 2048;
  const int rbc = (lr & 7) << 4;

  for (int t = 0; t < NT; ++t) {
    f32x4 acc  = {0.f, 0.f, 0.f, 0.f};
    f32x4 acc1 = {0.f, 0.f, 0.f, 0.f};

    // input term: A[row=lr][m] = u[b0+lr][t][m], zero-padded
    short8 ua;
    ua[0] = (short)f2bf(up0[0]); ua[1] = (short)f2bf(up0[1]);
    ua[2] = (short)f2bf(up0[2]); ua[3] = (short)f2bf(up0[3]);
    ua[4] = (short)f2bf(up1[0]); ua[5] = (short)f2bf(up1[1]);
    ua[6] = (short)f2bf(up1[2]); ua[7] = (short)f2bf(up1[3]);
    if (lg >= 3) ua = short8{0,0,0,0,0,0,0,0};
    acc = MF(ua, bin, acc);

    // recurrent GEMM: A fragments from the swizzled LDS tile (shared by 8 waves)
#pragma unroll
    for (int kb = 0; kb < 32; kb += 2) {
      short8 a0 = *(const short8*)(lrow + ((kb * 64 + lg * 16) ^ rbc));
      short8 a1 = *(const short8*)(lrow + (((kb + 1) * 64 + lg * 16) ^ rbc));
      acc  = MF(a0, wf[kb],     acc);
      acc1 = MF(a1, wf[kb + 1], acc1);
    }

    // state update (act = 60*sigmoid(0.28x-8.4) via native exp2)
    f32x4 rv;
#pragma unroll
    for (int q = 0; q < 4; ++q) {
      const float pre = acc[q] + acc1[q];
      const float act = 60.0f / (1.0f + exp2f(12.118664f - 0.40395462f * pre));
      rv[q] = r[q] + (0.1f * (act - r[q])) * itau;
      r[q]  = rv[q];
    }

    if (t != NT - 1) {
      // publish tagged obs (fire-and-forget agent stores; no vmcnt, no flags)
      const unsigned tag2 = (unsigned)(t + 2);
      unsigned* gw = ((t + 1) & 1) ? gt1 : gt0;
#pragma unroll
      for (int q = 0; q < 4; ++q) {
        const unsigned vv =
            (unsigned)f2bf(rv[q] > 0.0f ? rv[q] : 0.0f) | (tag2 << 16);
        __hip_atomic_store(&gw[(lg * 4 + q) * NN + i], vv,
                           __ATOMIC_RELAXED, SCOPE_AGENT);
      }

      // off-critical-path: out stores + u prefetch (drain inside stage's wait)
#pragma unroll
      for (int q = 0; q < 4; ++q)
        out[((size_t)(b0 + lg * 4 + q) * NT + t) * NN + i] = rv[q];
      if (lg < 3) {
        const float* up = up_base + (t + 1) * NIN + lg * 8;
        up0 = *(const f32x4*)(up);
        up1 = *(const f32x4*)(up + 4);
      }

      __syncthreads();          // all waves done reading the old LDS tile
      // paced stage: by T0+(t+2)P every block has published tag t+2
      stage(gw, tag2, T0 + (unsigned long long)(t + 2) * P_ticks);
      __syncthreads();
    } else {
#pragma unroll
      for (int q = 0; q < 4; ++q)
        out[((size_t)(b0 + lg * 4 + q) * NT + t) * NN + i] = rv[q];
    }
  }

  // r_final
#pragma unroll
  for (int q = 0; q < 4; ++q)
    out[(size_t)NBATCH * NT * NN + (size_t)(b0 + lg * 4 + q) * NN + i] = r[q];
}

extern "C" void kernel_launch(void* const* d_in, const int* in_sizes, int n_in,
                              void* d_out, int out_size, void* d_ws, size_t ws_size,
                              hipStream_t stream) {
  const float* u   = (const float*)d_in[0];
  const float* r0  = (const float*)d_in[1];
  const float* W   = (const float*)d_in[2];
  const float* Bm  = (const float*)d_in[3];
  const float* tau = (const float*)d_in[4];
  const float* ds  = (const float*)d_in[5];
  float* out = (float*)d_out;

  unsigned* obs32 = (unsigned*)d_ws;

  // wall-clock rate (kHz) -> ticks per 1.8 us period; fallback 100 MHz RTC
  int wckhz = 0;
  if (hipDeviceGetAttribute(&wckhz, hipDeviceAttributeWallClockRate, 0)
          != hipSuccess || wckhz <= 0)
    wckhz = 100000;
  unsigned long long P_ticks =
      (unsigned long long)((1.8e-6) * (double)wckhz * 1000.0 + 0.5);
  if (P_ticks < 2) P_ticks = 2;

  // zero both epoch-tagged buffers every call (tags restart at 1 -> deterministic)
  hipMemsetAsync(d_ws, 0, 2 * OBS32 * sizeof(unsigned), stream);

  rnn_step_all<<<dim3(NG * NSLOT), dim3(512), 0, stream>>>(u, r0, W, Bm, tau, ds,
                                                           out, obs32, P_ticks);
}